// Round 3
// baseline (152.228 us; speedup 1.0000x reference)
//
#include <hip/hip_runtime.h>
#include <math.h>

// Deformation4D: N=1M gaussians, K_NB=10 neighbors, K_TOTAL=300 control points.
//
// v4:
// - monomial algebra (v2): sum_k w_k R(q_hat_k) is linear in M = sum w q q^T,
//   so per neighbor we gather only q_hat(16B) + b(16B), b = p + t - R*p.
// - LDS tables DE-INTERLEAVED at 16B stride (q at s4[cp], b at s4[K+cp]):
//   start bank = 4*cp % 32 -> 8 bank-groups. v3's 32B-stride interleave gave
//   only 4 groups and doubled per-read conflicts (measured 16.5 extra cy/read).
// - pair processing (v3): 80B idx/weight rows for 2 gaussians load as
//   5x int4 + 5x float4; means as float2; quats as float4.
// - persistent grid (1536 blocks, grid-stride): table built once per resident
//   block instead of once per 512 gaussians; steadier wave residency.
// - all streaming loads issued before the LDS gather chain.

__device__ __forceinline__ void compute_cp(
    const float* __restrict__ ctrl_trans,
    const float* __restrict__ ctrl_rot,
    const float* __restrict__ ctrl_pos,
    int cp, float4* q_out, float4* b_out)
{
    float4 qv = ((const float4*)ctrl_rot)[cp];
    float qw = qv.x, qx = qv.y, qy = qv.z, qz = qv.w;
    float n   = sqrtf(qw * qw + qx * qx + qy * qy + qz * qz);
    float inv = 1.0f / fmaxf(n, 1e-8f);
    float w = qw * inv, x = qx * inv, y = qy * inv, z = qz * inv;
    float R00 = 1.0f - 2.0f * (y * y + z * z);
    float R01 = 2.0f * (x * y - w * z);
    float R02 = 2.0f * (x * z + w * y);
    float R10 = 2.0f * (x * y + w * z);
    float R11 = 1.0f - 2.0f * (x * x + z * z);
    float R12 = 2.0f * (y * z - w * x);
    float R20 = 2.0f * (x * z - w * y);
    float R21 = 2.0f * (y * z + w * x);
    float R22 = 1.0f - 2.0f * (x * x + y * y);
    float px = ctrl_pos[cp * 3 + 0];
    float py = ctrl_pos[cp * 3 + 1];
    float pz = ctrl_pos[cp * 3 + 2];
    float tx = ctrl_trans[cp * 3 + 0];
    float ty = ctrl_trans[cp * 3 + 1];
    float tz = ctrl_trans[cp * 3 + 2];
    *q_out = make_float4(w, x, y, z);
    *b_out = make_float4(px + tx - (R00 * px + R01 * py + R02 * pz),
                         py + ty - (R10 * px + R11 * py + R12 * pz),
                         pz + tz - (R20 * px + R21 * py + R22 * pz),
                         0.0f);
}

struct Accum {
    float W;
    float Mxx, Myy, Mzz, Mxy, Mxz, Myz, Mwx, Mwy, Mwz;
    float qsw, qsx, qsy, qsz;
    float bsx, bsy, bsz;
};

__device__ __forceinline__ void acc_init(Accum& a) {
    a.W = 0.0f;
    a.Mxx = a.Myy = a.Mzz = 0.0f;
    a.Mxy = a.Mxz = a.Myz = 0.0f;
    a.Mwx = a.Mwy = a.Mwz = 0.0f;
    a.qsw = a.qsx = a.qsy = a.qsz = 0.0f;
    a.bsx = a.bsy = a.bsz = 0.0f;
}

__device__ __forceinline__ void acc_neighbor(Accum& a, const float4* __restrict__ s4,
                                             int K_TOTAL, int cp, float w) {
    float4 q = s4[cp];             // (w,x,y,z) normalized; 16B stride
    float4 b = s4[K_TOTAL + cp];   // (bx,by,bz,_); same addr + const offset
    float tw = w * q.x, tx = w * q.y, ty = w * q.z, tz = w * q.w;
    a.W += w;
    a.Mxx = fmaf(tx, q.y, a.Mxx);
    a.Myy = fmaf(ty, q.z, a.Myy);
    a.Mzz = fmaf(tz, q.w, a.Mzz);
    a.Mxy = fmaf(tx, q.z, a.Mxy);
    a.Mxz = fmaf(tx, q.w, a.Mxz);
    a.Myz = fmaf(ty, q.w, a.Myz);
    a.Mwx = fmaf(tw, q.y, a.Mwx);
    a.Mwy = fmaf(tw, q.z, a.Mwy);
    a.Mwz = fmaf(tw, q.w, a.Mwz);
    a.qsw += tw; a.qsx += tx; a.qsy += ty; a.qsz += tz;
    a.bsx = fmaf(w, b.x, a.bsx);
    a.bsy = fmaf(w, b.y, a.bsy);
    a.bsz = fmaf(w, b.z, a.bsz);
}

__device__ __forceinline__ void acc_epilogue(const Accum& a,
                                             float mx, float my, float mz,
                                             float4 g,
                                             float* dmx, float* dmy, float* dmz,
                                             float4* oq) {
    float A00 = a.W - 2.0f * (a.Myy + a.Mzz);
    float A01 = 2.0f * (a.Mxy - a.Mwz);
    float A02 = 2.0f * (a.Mxz + a.Mwy);
    float A10 = 2.0f * (a.Mxy + a.Mwz);
    float A11 = a.W - 2.0f * (a.Mxx + a.Mzz);
    float A12 = 2.0f * (a.Myz - a.Mwx);
    float A20 = 2.0f * (a.Mxz - a.Mwy);
    float A21 = 2.0f * (a.Myz + a.Mwx);
    float A22 = a.W - 2.0f * (a.Mxx + a.Myy);

    *dmx = fmaf(A00, mx, fmaf(A01, my, fmaf(A02, mz, a.bsx)));
    *dmy = fmaf(A10, mx, fmaf(A11, my, fmaf(A12, mz, a.bsy)));
    *dmz = fmaf(A20, mx, fmaf(A21, my, fmaf(A22, mz, a.bsz)));

    float n   = sqrtf(a.qsw * a.qsw + a.qsx * a.qsx + a.qsy * a.qsy + a.qsz * a.qsz);
    float inv = 1.0f / fmaxf(n, 1e-8f);
    float bw = a.qsw * inv, bx = a.qsx * inv, by = a.qsy * inv, bz = a.qsz * inv;

    float gw = g.x, gx = g.y, gy = g.z, gz = g.w;
    oq->x = bw * gw - bx * gx - by * gy - bz * gz;
    oq->y = bw * gx + bx * gw + by * gz - bz * gy;
    oq->z = bw * gy - bx * gz + by * gw + bz * gx;
    oq->w = bw * gz + bx * gy - by * gx + bz * gw;
}

// Fast path: KNB=10, 2 gaussians/thread, persistent grid-stride loop.
__global__ __launch_bounds__(256) void deform_pair_kernel(
    const float* __restrict__ means,
    const float* __restrict__ quats,
    const float* __restrict__ weights,
    const float* __restrict__ ctrl_trans,
    const float* __restrict__ ctrl_rot,
    const float* __restrict__ ctrl_pos,
    const int*   __restrict__ indices,
    float* __restrict__ out_means,
    float* __restrict__ out_quats,
    int N, int K_TOTAL, long long n_pairs)
{
    extern __shared__ float4 s4[];
    for (int cp = threadIdx.x; cp < K_TOTAL; cp += blockDim.x) {
        float4 q, b;
        compute_cp(ctrl_trans, ctrl_rot, ctrl_pos, cp, &q, &b);
        s4[cp]           = q;
        s4[K_TOTAL + cp] = b;
    }
    __syncthreads();

    long long stride = (long long)gridDim.x * blockDim.x;
    for (long long p = (long long)blockIdx.x * blockDim.x + threadIdx.x;
         p < n_pairs; p += stride) {
        long long i0 = 2 * p;

        if (i0 + 1 < N) {
            // issue ALL streaming loads up front (independent of gathers)
            const int4*   ip = (const int4*)(indices + i0 * 10);
            const float4* wp = (const float4*)(weights + i0 * 10);
            int4   I0 = ip[0], I1 = ip[1], I2 = ip[2], I3 = ip[3], I4 = ip[4];
            float4 W0 = wp[0], W1 = wp[1], W2 = wp[2], W3 = wp[3], W4 = wp[4];
            const float2* mp = (const float2*)(means + i0 * 3);
            float2 m01 = mp[0], m23 = mp[1], m45 = mp[2];
            float4 g0 = ((const float4*)quats)[i0];
            float4 g1 = ((const float4*)quats)[i0 + 1];

            Accum a0; acc_init(a0);
            acc_neighbor(a0, s4, K_TOTAL, I0.x, W0.x);
            acc_neighbor(a0, s4, K_TOTAL, I0.y, W0.y);
            acc_neighbor(a0, s4, K_TOTAL, I0.z, W0.z);
            acc_neighbor(a0, s4, K_TOTAL, I0.w, W0.w);
            acc_neighbor(a0, s4, K_TOTAL, I1.x, W1.x);
            acc_neighbor(a0, s4, K_TOTAL, I1.y, W1.y);
            acc_neighbor(a0, s4, K_TOTAL, I1.z, W1.z);
            acc_neighbor(a0, s4, K_TOTAL, I1.w, W1.w);
            acc_neighbor(a0, s4, K_TOTAL, I2.x, W2.x);
            acc_neighbor(a0, s4, K_TOTAL, I2.y, W2.y);

            Accum a1; acc_init(a1);
            acc_neighbor(a1, s4, K_TOTAL, I2.z, W2.z);
            acc_neighbor(a1, s4, K_TOTAL, I2.w, W2.w);
            acc_neighbor(a1, s4, K_TOTAL, I3.x, W3.x);
            acc_neighbor(a1, s4, K_TOTAL, I3.y, W3.y);
            acc_neighbor(a1, s4, K_TOTAL, I3.z, W3.z);
            acc_neighbor(a1, s4, K_TOTAL, I3.w, W3.w);
            acc_neighbor(a1, s4, K_TOTAL, I4.x, W4.x);
            acc_neighbor(a1, s4, K_TOTAL, I4.y, W4.y);
            acc_neighbor(a1, s4, K_TOTAL, I4.z, W4.z);
            acc_neighbor(a1, s4, K_TOTAL, I4.w, W4.w);

            float d0x, d0y, d0z, d1x, d1y, d1z;
            float4 oq0, oq1;
            acc_epilogue(a0, m01.x, m01.y, m23.x, g0, &d0x, &d0y, &d0z, &oq0);
            acc_epilogue(a1, m23.y, m45.x, m45.y, g1, &d1x, &d1y, &d1z, &oq1);

            float2* omp = (float2*)(out_means + i0 * 3);
            omp[0] = make_float2(d0x, d0y);
            omp[1] = make_float2(d0z, d1x);
            omp[2] = make_float2(d1y, d1z);

            float4* oqp = (float4*)(out_quats + i0 * 4);
            oqp[0] = oq0;
            oqp[1] = oq1;
        } else {
            // tail: single gaussian (N odd)
            const int*   idx_row = indices + i0 * 10;
            const float* w_row   = weights + i0 * 10;
            Accum a0; acc_init(a0);
#pragma unroll
            for (int k = 0; k < 10; k++)
                acc_neighbor(a0, s4, K_TOTAL, idx_row[k], w_row[k]);

            float mx = means[i0 * 3 + 0];
            float my = means[i0 * 3 + 1];
            float mz = means[i0 * 3 + 2];
            float4 g0 = ((const float4*)quats)[i0];
            float dx, dy, dz;
            float4 oq0;
            acc_epilogue(a0, mx, my, mz, g0, &dx, &dy, &dz, &oq0);
            out_means[i0 * 3 + 0] = dx;
            out_means[i0 * 3 + 1] = dy;
            out_means[i0 * 3 + 2] = dz;
            ((float4*)out_quats)[i0] = oq0;
        }
    }
}

// Generic fallback: runtime K_NB, 1 gaussian per thread.
__global__ __launch_bounds__(256) void deform_generic_kernel(
    const float* __restrict__ means,
    const float* __restrict__ quats,
    const float* __restrict__ weights,
    const float* __restrict__ ctrl_trans,
    const float* __restrict__ ctrl_rot,
    const float* __restrict__ ctrl_pos,
    const int*   __restrict__ indices,
    float* __restrict__ out_means,
    float* __restrict__ out_quats,
    int N, int K_NB, int K_TOTAL)
{
    extern __shared__ float4 s4[];
    for (int cp = threadIdx.x; cp < K_TOTAL; cp += blockDim.x) {
        float4 q, b;
        compute_cp(ctrl_trans, ctrl_rot, ctrl_pos, cp, &q, &b);
        s4[cp]           = q;
        s4[K_TOTAL + cp] = b;
    }
    __syncthreads();

    long long i = (long long)blockIdx.x * blockDim.x + threadIdx.x;
    if (i >= N) return;

    const int*   idx_row = indices + i * K_NB;
    const float* w_row   = weights + i * K_NB;
    Accum a0; acc_init(a0);
    for (int k = 0; k < K_NB; k++)
        acc_neighbor(a0, s4, K_TOTAL, idx_row[k], w_row[k]);

    float mx = means[i * 3 + 0];
    float my = means[i * 3 + 1];
    float mz = means[i * 3 + 2];
    float4 g0 = ((const float4*)quats)[i];
    float dx, dy, dz;
    float4 oq0;
    acc_epilogue(a0, mx, my, mz, g0, &dx, &dy, &dz, &oq0);
    out_means[i * 3 + 0] = dx;
    out_means[i * 3 + 1] = dy;
    out_means[i * 3 + 2] = dz;
    ((float4*)out_quats)[i] = oq0;
}

extern "C" void kernel_launch(void* const* d_in, const int* in_sizes, int n_in,
                              void* d_out, int out_size, void* d_ws, size_t ws_size,
                              hipStream_t stream) {
    const float* means      = (const float*)d_in[0];
    const float* quats      = (const float*)d_in[1];
    const float* weights    = (const float*)d_in[2];
    const float* ctrl_trans = (const float*)d_in[3];
    const float* ctrl_rot   = (const float*)d_in[4];
    const float* ctrl_pos   = (const float*)d_in[5];
    const int*   indices    = (const int*)d_in[6];

    int N       = in_sizes[0] / 3;
    int K_NB    = in_sizes[2] / N;       // weights is N*K_NB
    int K_TOTAL = in_sizes[3] / 3;       // ctrl_translations is K_TOTAL*3

    float* out_means = (float*)d_out;
    float* out_quats = (float*)d_out + (long long)N * 3;

    int block = 256;
    size_t smem = (size_t)K_TOTAL * 2 * sizeof(float4);

    if (K_NB == 10) {
        long long n_pairs = ((long long)N + 1) / 2;
        long long blocks  = (n_pairs + block - 1) / block;
        int grid = (int)(blocks < 1536 ? blocks : 1536);   // 256 CU x 6 blocks
        deform_pair_kernel<<<grid, block, smem, stream>>>(
            means, quats, weights, ctrl_trans, ctrl_rot, ctrl_pos, indices,
            out_means, out_quats, N, K_TOTAL, n_pairs);
    } else {
        int grid = (int)(((long long)N + block - 1) / block);
        deform_generic_kernel<<<grid, block, smem, stream>>>(
            means, quats, weights, ctrl_trans, ctrl_rot, ctrl_pos, indices,
            out_means, out_quats, N, K_NB, K_TOTAL);
    }
}

// Round 4
// 148.752 us; speedup vs baseline: 1.0234x; 1.0234x over previous
//
#include <hip/hip_runtime.h>
#include <math.h>

// Deformation4D: N=1M gaussians, K_NB=10 neighbors, K_TOTAL=300 control points.
//
// v5: attack VMEM request divergence. All previous versions loaded idx/weight
// rows with lane-strided instructions (40-80B/lane stride -> each 64-lane load
// touches 40-64 cache lines -> TA/L1 serializes per lane). v5 stages the
// block's idx+weights (20KB) through LDS with UNIT-STRIDE dwordx4 loads
// (1 line per 4 lanes) + contiguous conflict-free ds_write_b128, then each
// thread reads its own 40B row from LDS (ds_read2_b64, <=4-way conflicts).
//
// Kept from v4: monomial algebra (gather q(16B)+b(16B) per neighbor, rebuild
// sum(wR) in epilogue), 16B-stride de-interleaved table (8 bank-groups).
// Reverted from v4: pairing (VGPR bloat, no benefit), persistent grid.

struct Accum {
    float W;
    float Mxx, Myy, Mzz, Mxy, Mxz, Myz, Mwx, Mwy, Mwz;
    float qsw, qsx, qsy, qsz;
    float bsx, bsy, bsz;
};

__device__ __forceinline__ void acc_init(Accum& a) {
    a.W = 0.0f;
    a.Mxx = a.Myy = a.Mzz = 0.0f;
    a.Mxy = a.Mxz = a.Myz = 0.0f;
    a.Mwx = a.Mwy = a.Mwz = 0.0f;
    a.qsw = a.qsx = a.qsy = a.qsz = 0.0f;
    a.bsx = a.bsy = a.bsz = 0.0f;
}

__device__ __forceinline__ void acc_neighbor(Accum& a, const float4* __restrict__ tbl,
                                             int K_TOTAL, int cp, float w) {
    float4 q = tbl[cp];             // (w,x,y,z) normalized; 16B stride
    float4 b = tbl[K_TOTAL + cp];   // (bx,by,bz,_)
    float tw = w * q.x, tx = w * q.y, ty = w * q.z, tz = w * q.w;
    a.W += w;
    a.Mxx = fmaf(tx, q.y, a.Mxx);
    a.Myy = fmaf(ty, q.z, a.Myy);
    a.Mzz = fmaf(tz, q.w, a.Mzz);
    a.Mxy = fmaf(tx, q.z, a.Mxy);
    a.Mxz = fmaf(tx, q.w, a.Mxz);
    a.Myz = fmaf(ty, q.w, a.Myz);
    a.Mwx = fmaf(tw, q.y, a.Mwx);
    a.Mwy = fmaf(tw, q.z, a.Mwy);
    a.Mwz = fmaf(tw, q.w, a.Mwz);
    a.qsw += tw; a.qsx += tx; a.qsy += ty; a.qsz += tz;
    a.bsx = fmaf(w, b.x, a.bsx);
    a.bsy = fmaf(w, b.y, a.bsy);
    a.bsz = fmaf(w, b.z, a.bsz);
}

__device__ __forceinline__ void acc_epilogue(const Accum& a,
                                             float mx, float my, float mz,
                                             float4 g,
                                             float* dmx, float* dmy, float* dmz,
                                             float4* oq) {
    float A00 = a.W - 2.0f * (a.Myy + a.Mzz);
    float A01 = 2.0f * (a.Mxy - a.Mwz);
    float A02 = 2.0f * (a.Mxz + a.Mwy);
    float A10 = 2.0f * (a.Mxy + a.Mwz);
    float A11 = a.W - 2.0f * (a.Mxx + a.Mzz);
    float A12 = 2.0f * (a.Myz - a.Mwx);
    float A20 = 2.0f * (a.Mxz - a.Mwy);
    float A21 = 2.0f * (a.Myz + a.Mwx);
    float A22 = a.W - 2.0f * (a.Mxx + a.Myy);

    *dmx = fmaf(A00, mx, fmaf(A01, my, fmaf(A02, mz, a.bsx)));
    *dmy = fmaf(A10, mx, fmaf(A11, my, fmaf(A12, mz, a.bsy)));
    *dmz = fmaf(A20, mx, fmaf(A21, my, fmaf(A22, mz, a.bsz)));

    float n   = sqrtf(a.qsw * a.qsw + a.qsx * a.qsx + a.qsy * a.qsy + a.qsz * a.qsz);
    float inv = 1.0f / fmaxf(n, 1e-8f);
    float bw = a.qsw * inv, bx = a.qsx * inv, by = a.qsy * inv, bz = a.qsz * inv;

    float gw = g.x, gx = g.y, gy = g.z, gz = g.w;
    oq->x = bw * gw - bx * gx - by * gy - bz * gz;
    oq->y = bw * gx + bx * gw + by * gz - bz * gy;
    oq->z = bw * gy - bx * gz + by * gw + bz * gx;
    oq->w = bw * gz + bx * gy - by * gx + bz * gw;
}

__device__ __forceinline__ void build_table(
    const float* __restrict__ ctrl_trans,
    const float* __restrict__ ctrl_rot,
    const float* __restrict__ ctrl_pos,
    float4* __restrict__ tbl, int K_TOTAL)
{
    for (int cp = threadIdx.x; cp < K_TOTAL; cp += blockDim.x) {
        float4 qv = ((const float4*)ctrl_rot)[cp];
        float qw = qv.x, qx = qv.y, qy = qv.z, qz = qv.w;
        float nn  = sqrtf(qw * qw + qx * qx + qy * qy + qz * qz);
        float inv = 1.0f / fmaxf(nn, 1e-8f);
        float w = qw * inv, x = qx * inv, y = qy * inv, z = qz * inv;
        float R00 = 1.0f - 2.0f * (y * y + z * z);
        float R01 = 2.0f * (x * y - w * z);
        float R02 = 2.0f * (x * z + w * y);
        float R10 = 2.0f * (x * y + w * z);
        float R11 = 1.0f - 2.0f * (x * x + z * z);
        float R12 = 2.0f * (y * z - w * x);
        float R20 = 2.0f * (x * z - w * y);
        float R21 = 2.0f * (y * z + w * x);
        float R22 = 1.0f - 2.0f * (x * x + y * y);
        float px = ctrl_pos[cp * 3 + 0];
        float py = ctrl_pos[cp * 3 + 1];
        float pz = ctrl_pos[cp * 3 + 2];
        float tx = ctrl_trans[cp * 3 + 0];
        float ty = ctrl_trans[cp * 3 + 1];
        float tz = ctrl_trans[cp * 3 + 2];
        tbl[cp]           = make_float4(w, x, y, z);
        tbl[K_TOTAL + cp] = make_float4(px + tx - (R00 * px + R01 * py + R02 * pz),
                                        py + ty - (R10 * px + R11 * py + R12 * pz),
                                        pz + tz - (R20 * px + R21 * py + R22 * pz),
                                        0.0f);
    }
}

// Fast path: K_NB=10. Block of 256 handles 256 gaussians; idx/weights staged
// through LDS with unit-stride loads.
__global__ __launch_bounds__(256) void deform_stage_kernel(
    const float* __restrict__ means,
    const float* __restrict__ quats,
    const float* __restrict__ weights,
    const float* __restrict__ ctrl_trans,
    const float* __restrict__ ctrl_rot,
    const float* __restrict__ ctrl_pos,
    const int*   __restrict__ indices,
    float* __restrict__ out_means,
    float* __restrict__ out_quats,
    int N, int K_TOTAL)
{
    extern __shared__ float smem[];
    float4* tbl  = (float4*)smem;            // 2*K_TOTAL float4
    float*  sIdx = smem + 8 * K_TOTAL;       // 2560 floats (int bits)
    float*  sW   = sIdx + 2560;              // 2560 floats

    const int t = threadIdx.x;
    const long long blockBase = (long long)blockIdx.x * 256;
    const long long fbase = blockBase * 10;       // float index of block's row 0
    const long long ftot  = (long long)N * 10;    // total floats per stream

    // ---- stage idx + weights: unit-stride float4 loads, contiguous b128 writes
    // 640 float4 per stream per block; full blocks take the vector path.
#pragma unroll
    for (int j = t; j < 640; j += 256) {
        long long f0 = fbase + 4LL * j;
        float4 vi, vw;
        if (f0 + 3 < ftot) {
            vi = ((const float4*)indices)[f0 / 4];
            vw = ((const float4*)weights)[f0 / 4];
        } else {
            float ei[4], ew[4];
#pragma unroll
            for (int e = 0; e < 4; e++) {
                long long f = f0 + e;
                bool ok = f < ftot;
                ei[e] = ok ? ((const float*)indices)[f] : 0.0f;
                ew[e] = ok ? weights[f] : 0.0f;
            }
            vi = make_float4(ei[0], ei[1], ei[2], ei[3]);
            vw = make_float4(ew[0], ew[1], ew[2], ew[3]);
        }
        *(float4*)(sIdx + 4 * j) = vi;
        *(float4*)(sW   + 4 * j) = vw;
    }

    // ---- table build (overlaps staging latency) ----
    build_table(ctrl_trans, ctrl_rot, ctrl_pos, tbl, K_TOTAL);

    __syncthreads();

    long long g = blockBase + t;
    if (g >= N) return;

    // own row from LDS: 40B at t*40, 8B-aligned -> float2/int2 (ds_read2_b64)
    const int2*   ip2 = (const int2*)  (sIdx + t * 10);
    const float2* wp2 = (const float2*)(sW   + t * 10);
    int2   i01 = ip2[0], i23 = ip2[1], i45 = ip2[2], i67 = ip2[3], i89 = ip2[4];
    float2 w01 = wp2[0], w23 = wp2[1], w45 = wp2[2], w67 = wp2[3], w89 = wp2[4];

    // streaming per-gaussian data (issued before the gather chain)
    float mx = means[g * 3 + 0];
    float my = means[g * 3 + 1];
    float mz = means[g * 3 + 2];
    float4 gq = ((const float4*)quats)[g];

    Accum a; acc_init(a);
    acc_neighbor(a, tbl, K_TOTAL, i01.x, w01.x);
    acc_neighbor(a, tbl, K_TOTAL, i01.y, w01.y);
    acc_neighbor(a, tbl, K_TOTAL, i23.x, w23.x);
    acc_neighbor(a, tbl, K_TOTAL, i23.y, w23.y);
    acc_neighbor(a, tbl, K_TOTAL, i45.x, w45.x);
    acc_neighbor(a, tbl, K_TOTAL, i45.y, w45.y);
    acc_neighbor(a, tbl, K_TOTAL, i67.x, w67.x);
    acc_neighbor(a, tbl, K_TOTAL, i67.y, w67.y);
    acc_neighbor(a, tbl, K_TOTAL, i89.x, w89.x);
    acc_neighbor(a, tbl, K_TOTAL, i89.y, w89.y);

    float dx, dy, dz;
    float4 oq;
    acc_epilogue(a, mx, my, mz, gq, &dx, &dy, &dz, &oq);

    out_means[g * 3 + 0] = dx;
    out_means[g * 3 + 1] = dy;
    out_means[g * 3 + 2] = dz;
    ((float4*)out_quats)[g] = oq;
}

// Generic fallback: runtime K_NB, direct loads (unchanged from v4).
__global__ __launch_bounds__(256) void deform_generic_kernel(
    const float* __restrict__ means,
    const float* __restrict__ quats,
    const float* __restrict__ weights,
    const float* __restrict__ ctrl_trans,
    const float* __restrict__ ctrl_rot,
    const float* __restrict__ ctrl_pos,
    const int*   __restrict__ indices,
    float* __restrict__ out_means,
    float* __restrict__ out_quats,
    int N, int K_NB, int K_TOTAL)
{
    extern __shared__ float smem[];
    float4* tbl = (float4*)smem;
    build_table(ctrl_trans, ctrl_rot, ctrl_pos, tbl, K_TOTAL);
    __syncthreads();

    long long i = (long long)blockIdx.x * blockDim.x + threadIdx.x;
    if (i >= N) return;

    const int*   idx_row = indices + i * K_NB;
    const float* w_row   = weights + i * K_NB;
    Accum a; acc_init(a);
    for (int k = 0; k < K_NB; k++)
        acc_neighbor(a, tbl, K_TOTAL, idx_row[k], w_row[k]);

    float mx = means[i * 3 + 0];
    float my = means[i * 3 + 1];
    float mz = means[i * 3 + 2];
    float4 gq = ((const float4*)quats)[i];
    float dx, dy, dz;
    float4 oq;
    acc_epilogue(a, mx, my, mz, gq, &dx, &dy, &dz, &oq);
    out_means[i * 3 + 0] = dx;
    out_means[i * 3 + 1] = dy;
    out_means[i * 3 + 2] = dz;
    ((float4*)out_quats)[i] = oq;
}

extern "C" void kernel_launch(void* const* d_in, const int* in_sizes, int n_in,
                              void* d_out, int out_size, void* d_ws, size_t ws_size,
                              hipStream_t stream) {
    const float* means      = (const float*)d_in[0];
    const float* quats      = (const float*)d_in[1];
    const float* weights    = (const float*)d_in[2];
    const float* ctrl_trans = (const float*)d_in[3];
    const float* ctrl_rot   = (const float*)d_in[4];
    const float* ctrl_pos   = (const float*)d_in[5];
    const int*   indices    = (const int*)d_in[6];

    int N       = in_sizes[0] / 3;
    int K_NB    = in_sizes[2] / N;       // weights is N*K_NB
    int K_TOTAL = in_sizes[3] / 3;       // ctrl_translations is K_TOTAL*3

    float* out_means = (float*)d_out;
    float* out_quats = (float*)d_out + (long long)N * 3;

    int block = 256;
    int grid  = (int)(((long long)N + block - 1) / block);

    if (K_NB == 10) {
        // table (2*K_TOTAL float4) + idx stage (2560 f) + w stage (2560 f)
        size_t smem = (size_t)(8 * K_TOTAL + 5120) * sizeof(float);
        deform_stage_kernel<<<grid, block, smem, stream>>>(
            means, quats, weights, ctrl_trans, ctrl_rot, ctrl_pos, indices,
            out_means, out_quats, N, K_TOTAL);
    } else {
        size_t smem = (size_t)K_TOTAL * 2 * sizeof(float4);
        deform_generic_kernel<<<grid, block, smem, stream>>>(
            means, quats, weights, ctrl_trans, ctrl_rot, ctrl_pos, indices,
            out_means, out_quats, N, K_NB, K_TOTAL);
    }
}